// Round 1
// baseline (302.251 us; speedup 1.0000x reference)
//
#include <hip/hip_runtime.h>

#define TT    524288
#define CHUNK 512
#define NCH   (TT / CHUNK)     // 1024 chunks
#define SUB   64               // subtile rows
#define NSUB  (CHUNK / SUB)    // 8

typedef __attribute__((ext_vector_type(8))) short short8;
typedef __attribute__((ext_vector_type(4))) float f32x4;

__device__ __forceinline__ unsigned short f2bf(float f) {
    union { float f; unsigned u; } v; v.f = f;
    unsigned r = v.u + 0x7FFFu + ((v.u >> 16) & 1u);   // RTNE
    return (unsigned short)(r >> 16);
}
// pack (a,b) -> bf16(a) | bf16(b)<<16
__device__ __forceinline__ unsigned packbf2(float a, float b) {
    union { float f; unsigned u; } va, vb; va.f = a; vb.f = b;
    unsigned ra = va.u + 0x7FFFu + ((va.u >> 16) & 1u);
    unsigned rb = vb.u + 0x7FFFu + ((vb.u >> 16) & 1u);
    return (ra >> 16) | (rb & 0xFFFF0000u);
}
__device__ __forceinline__ float2 unpackbf2(unsigned w) {
    union { unsigned u; float f; } a, b;
    a.u = w << 16; b.u = w & 0xFFFF0000u;
    return make_float2(a.f, b.f);
}
__device__ __forceinline__ float sigf(float v) {
    return __builtin_amdgcn_rcpf(1.0f + __expf(-v));   // v_exp + v_rcp
}

// ============================================================================
// Phase A: one block = one chunk of 512 rows, 8 subtiles of 64.
// h = sigmoid(X@W1+B1) via bf16 MFMA; a=l*r, b=1-l packed bf16x2 in LDS;
// 4-wave segmented scan -> chunk map (A,B).
// NEW: exports packed (a,b) words to global (abg) in the exact per-thread
// layout ephase reads (coalesced dwordx4 both sides), so the emit pass never
// recomputes h. LDS = 46.9 KB -> 3 blocks/CU.
// ============================================================================
__global__ __launch_bounds__(256, 3)
void aphase(const float* __restrict__ x, const float* __restrict__ W1,
            const float* __restrict__ B1,
            float* __restrict__ Aout, float* __restrict__ Bout,
            uint4* __restrict__ abg)
{
    __shared__ __align__(16) short    W1t[128 * 72];  // W1^T bf16 [n][k] 18.4KB
    __shared__ float    B1s[128];
    __shared__ __align__(16) short    XZ[SUB * 72];   // X bf16 [m][k]
    __shared__ unsigned abp[SUB * 65];                // packed (a,b) [m][ch] 16.6KB
    __shared__ float    segA[4 * 66], segB[4 * 66];

    const int tid  = threadIdx.x;
    const int c    = blockIdx.x;
    const int wave = tid >> 6;
    const int lane = tid & 63;
    const int quad = lane >> 4;
    const int lr   = lane & 15;

    for (int i = tid; i < 2048; i += 256) {
        float4 w4 = ((const float4*)W1)[i];
        int k = i >> 5, n0 = (i & 31) * 4;
        W1t[(n0 + 0) * 72 + k] = (short)f2bf(w4.x);
        W1t[(n0 + 1) * 72 + k] = (short)f2bf(w4.y);
        W1t[(n0 + 2) * 72 + k] = (short)f2bf(w4.z);
        W1t[(n0 + 3) * 72 + k] = (short)f2bf(w4.w);
    }
    if (tid < 128) B1s[tid] = B1[tid];

    const float4* xg = (const float4*)(x + (size_t)c * CHUNK * 64);
    float4 xr0 = xg[tid], xr1 = xg[tid + 256], xr2 = xg[tid + 512], xr3 = xg[tid + 768];

    float sA = 1.0f, sB = 0.0f;   // running chunk map (tid<64)

    for (int s = 0; s < NSUB; ++s) {
        // ---- write prefetched subtile to LDS as bf16 ----
        {
            float4 v; int f;
#define PUTX(R, J) { v = (R); f = tid + 256 * (J); int row = f >> 4, c4 = (f & 15) * 4; \
            unsigned lo = (unsigned)f2bf(v.x) | ((unsigned)f2bf(v.y) << 16); \
            unsigned hi = (unsigned)f2bf(v.z) | ((unsigned)f2bf(v.w) << 16); \
            *(uint2*)&XZ[row * 72 + c4] = make_uint2(lo, hi); }
            PUTX(xr0, 0) PUTX(xr1, 1) PUTX(xr2, 2) PUTX(xr3, 3)
#undef PUTX
        }
        __syncthreads();   // A

        if (s + 1 < NSUB) {
            const float4* xn = xg + (size_t)(s + 1) * 1024;
            xr0 = xn[tid]; xr1 = xn[tid + 256]; xr2 = xn[tid + 512]; xr3 = xn[tid + 768];
        }

        // ---- MFMA: wave w owns rows w*16..+15, all 8 col-tiles ----
        f32x4 acc[8];
        #pragma unroll
        for (int j = 0; j < 8; ++j) {
            float b = B1s[j * 16 + lr];
            acc[j][0] = b; acc[j][1] = b; acc[j][2] = b; acc[j][3] = b;
        }
        const short8 a0 = *(const short8*)&XZ[(wave * 16 + lr) * 72 + quad * 8];
        const short8 a1 = *(const short8*)&XZ[(wave * 16 + lr) * 72 + quad * 8 + 32];
        #pragma unroll
        for (int j = 0; j < 8; ++j) {
            const short8 b0 = *(const short8*)&W1t[(j * 16 + lr) * 72 + quad * 8];
            const short8 b1 = *(const short8*)&W1t[(j * 16 + lr) * 72 + quad * 8 + 32];
            acc[j] = __builtin_amdgcn_mfma_f32_16x16x32_bf16(a0, b0, acc[j], 0, 0, 0);
            acc[j] = __builtin_amdgcn_mfma_f32_16x16x32_bf16(a1, b1, acc[j], 0, 0, 0);
        }

        // ---- sigmoid; a=l*r, b=1-l; pack bf16x2 -> abp[m][ch] ----
        #pragma unroll
        for (int j = 0; j < 4; ++j) {
            #pragma unroll
            for (int r = 0; r < 4; ++r) {
                float hl = sigf(acc[j][r]);
                float hr = sigf(acc[j + 4][r]);
                int m = wave * 16 + quad * 4 + r;
                abp[m * 65 + j * 16 + lr] = packbf2(hl * hr, 1.0f - hl);
            }
        }
        __syncthreads();   // B

        // ---- export packed ab to global in ephase's read layout ----
        {
            uint4* dst = abg + ((size_t)((c * NSUB + s) * 16 + wave * 4)) * 64 + lane;
            #pragma unroll
            for (int i = 0; i < 4; ++i) {
                uint4 v;
                v.x = abp[(wave * 16 + i * 4 + 0) * 65 + lane];
                v.y = abp[(wave * 16 + i * 4 + 1) * 65 + lane];
                v.z = abp[(wave * 16 + i * 4 + 2) * 65 + lane];
                v.w = abp[(wave * 16 + i * 4 + 3) * 65 + lane];
                dst[i * 64] = v;
            }
        }

        // ---- segmented composition: wave w composes its 16 rows ----
        float A = 1.0f, Bv = 0.0f;
        #pragma unroll
        for (int t = 0; t < 16; ++t) {
            float2 f2 = unpackbf2(abp[(wave * 16 + t) * 65 + lane]);
            Bv = fmaf(f2.x, Bv, f2.y); A *= f2.x;
        }
        segA[wave * 66 + lane] = A;
        segB[wave * 66 + lane] = Bv;
        __syncthreads();   // C

        if (tid < 64) {
            #pragma unroll
            for (int q = 0; q < 4; ++q) {
                float A2 = segA[q * 66 + tid], B2v = segB[q * 66 + tid];
                sB = fmaf(A2, sB, B2v); sA *= A2;
            }
        }
    }

    if (tid < 64) { Aout[c * 64 + tid] = sA; Bout[c * 64 + tid] = sB; }
}

// ============================================================================
// Carry scan across 1024 chunk maps: 16 parallel segments of 64 (1024 thr).
// ============================================================================
__global__ void carry_scan(const float* __restrict__ Aar, const float* __restrict__ Bar,
                           float* __restrict__ carry)
{
    __shared__ float sA[16 * 66], sB[16 * 66];
    const int tid = threadIdx.x;
    const int ch = tid & 63, seg = tid >> 6;       // 16 segments
    const int c0 = seg * (NCH / 16);

    float A = 1.0f, B = 0.0f;
    #pragma unroll 8
    for (int i = 0; i < NCH / 16; ++i) {
        const int idx = c0 + i;
        const float a = Aar[idx * 64 + ch];
        const float b = Bar[idx * 64 + ch];
        B = fmaf(a, B, b); A *= a;
    }
    sA[seg * 66 + ch] = A;
    sB[seg * 66 + ch] = B;
    __syncthreads();

    float u = 0.0f;
    #pragma unroll
    for (int q = 0; q < 15; ++q)
        if (q < seg) u = fmaf(sA[q * 66 + ch], u, sB[q * 66 + ch]);
    #pragma unroll 8
    for (int i = 0; i < NCH / 16; ++i) {
        const int idx = c0 + i;
        carry[idx * 64 + ch] = u;
        u = fmaf(Aar[idx * 64 + ch], u, Bar[idx * 64 + ch]);
    }
}

// ============================================================================
// Phase E (emit): reads packed ab straight into registers (4 coalesced uint4
// per thread per subtile), scans, stages z in LDS, out = Z@W2 + B2 via MFMA.
// No h recompute, no x read. Double-buffered seg/ucur -> ONE barrier/subtile.
// LDS = 18.7 KB, light VGPR -> high occupancy; should run near HBM BW.
// ============================================================================
__global__ __launch_bounds__(256, 4)
void ephase(const uint4* __restrict__ abg, const float* __restrict__ carry,
            const float* __restrict__ W2, const float* __restrict__ B2,
            float* __restrict__ out)
{
    __shared__ __align__(16) short Zs[SUB * 72];       // z bf16 [m][k] 9.2KB
    __shared__ float segA[2 * 4 * 66], segB[2 * 4 * 66];
    __shared__ __align__(16) short W2t[32 * 72];       // W2^T bf16 [n][k]
    __shared__ float B2s[32];
    __shared__ float ucur[2 * 64];

    const int tid  = threadIdx.x;
    const int c    = blockIdx.x;
    const int wave = tid >> 6;
    const int lane = tid & 63;
    const int quad = lane >> 4;
    const int lr   = lane & 15;

    for (int i = tid; i < 512; i += 256) {
        float4 w4 = ((const float4*)W2)[i];
        int k = i >> 3, n0 = (i & 7) * 4;
        W2t[(n0 + 0) * 72 + k] = (short)f2bf(w4.x);
        W2t[(n0 + 1) * 72 + k] = (short)f2bf(w4.y);
        W2t[(n0 + 2) * 72 + k] = (short)f2bf(w4.z);
        W2t[(n0 + 3) * 72 + k] = (short)f2bf(w4.w);
    }
    if (tid < 32) B2s[tid] = B2[tid];
    if (tid < 64) ucur[tid] = carry[c * 64 + tid];     // ucur[0][*]
    // first reads of all staged LDS happen after the s=0 barrier below.

    const uint4* ag = abg + (size_t)c * (NSUB * 16 * 64);
    uint4 r0 = ag[(wave * 4 + 0) * 64 + lane];
    uint4 r1 = ag[(wave * 4 + 1) * 64 + lane];
    uint4 r2 = ag[(wave * 4 + 2) * 64 + lane];
    uint4 r3 = ag[(wave * 4 + 3) * 64 + lane];

    for (int s = 0; s < NSUB; ++s) {
        const int pb = (s & 1) * 264;                  // seg buffer parity
        // ---- compose own 16 rows from registers ----
        float A = 1.0f, Bv = 0.0f; float2 f;
#define CSTEP(W) { f = unpackbf2(W); Bv = fmaf(f.x, Bv, f.y); A *= f.x; }
        CSTEP(r0.x) CSTEP(r0.y) CSTEP(r0.z) CSTEP(r0.w)
        CSTEP(r1.x) CSTEP(r1.y) CSTEP(r1.z) CSTEP(r1.w)
        CSTEP(r2.x) CSTEP(r2.y) CSTEP(r2.z) CSTEP(r2.w)
        CSTEP(r3.x) CSTEP(r3.y) CSTEP(r3.z) CSTEP(r3.w)
#undef CSTEP
        segA[pb + wave * 66 + lane] = A;
        segB[pb + wave * 66 + lane] = Bv;
        __syncthreads();   // the only barrier per subtile

        // ---- per-wave prefix from carry-in ----
        float u = ucur[(s & 1) * 64 + lane];
        #pragma unroll
        for (int q = 0; q < 3; ++q)
            if (q < wave) u = fmaf(segA[pb + q * 66 + lane], u, segB[pb + q * 66 + lane]);

        // ---- emit z into own 16-row band of Zs ----
        int t = 0;
#define ESTEP(W) { Zs[(wave * 16 + t) * 72 + lane] = (short)f2bf(u); \
                   f = unpackbf2(W); u = fmaf(f.x, u, f.y); ++t; }
        ESTEP(r0.x) ESTEP(r0.y) ESTEP(r0.z) ESTEP(r0.w)
        ESTEP(r1.x) ESTEP(r1.y) ESTEP(r1.z) ESTEP(r1.w)
        ESTEP(r2.x) ESTEP(r2.y) ESTEP(r2.z) ESTEP(r2.w)
        ESTEP(r3.x) ESTEP(r3.y) ESTEP(r3.z) ESTEP(r3.w)
#undef ESTEP
        if (wave == 3) ucur[((s + 1) & 1) * 64 + lane] = u;   // other parity

        // ---- prefetch next subtile's ab (latency hidden under out-GEMM) ----
        if (s + 1 < NSUB) {
            const uint4* an = ag + (size_t)(s + 1) * (16 * 64);
            r0 = an[(wave * 4 + 0) * 64 + lane];
            r1 = an[(wave * 4 + 1) * 64 + lane];
            r2 = an[(wave * 4 + 2) * 64 + lane];
            r3 = an[(wave * 4 + 3) * 64 + lane];
        }

        // ---- out = Z @ W2 + B2 via MFMA (reads own band only) ----
        const short8 za0 = *(const short8*)&Zs[(wave * 16 + lr) * 72 + quad * 8];
        const short8 za1 = *(const short8*)&Zs[(wave * 16 + lr) * 72 + quad * 8 + 32];
        const size_t row0g = (size_t)c * CHUNK + (size_t)s * SUB;
        #pragma unroll
        for (int nt = 0; nt < 2; ++nt) {
            f32x4 cc;
            float b = B2s[nt * 16 + lr];
            cc[0] = b; cc[1] = b; cc[2] = b; cc[3] = b;
            const short8 b0 = *(const short8*)&W2t[(nt * 16 + lr) * 72 + quad * 8];
            const short8 b1 = *(const short8*)&W2t[(nt * 16 + lr) * 72 + quad * 8 + 32];
            cc = __builtin_amdgcn_mfma_f32_16x16x32_bf16(za0, b0, cc, 0, 0, 0);
            cc = __builtin_amdgcn_mfma_f32_16x16x32_bf16(za1, b1, cc, 0, 0, 0);
            #pragma unroll
            for (int r = 0; r < 4; ++r) {
                int m = wave * 16 + quad * 4 + r;
                out[(row0g + m) * 32 + nt * 16 + lr] = cc[r];
            }
        }
        // no trailing barrier: seg/ucur are parity double-buffered; Zs is
        // same-wave only; next overwrite of this parity is separated by the
        // next iteration's barrier.
    }
}

extern "C" void kernel_launch(void* const* d_in, const int* in_sizes, int n_in,
                              void* d_out, int out_size, void* d_ws, size_t ws_size,
                              hipStream_t stream)
{
    const float* x  = (const float*)d_in[0];
    const float* W1 = (const float*)d_in[1];
    const float* B1 = (const float*)d_in[2];
    const float* W2 = (const float*)d_in[3];
    const float* B2 = (const float*)d_in[4];
    float* out = (float*)d_out;

    float* Aar   = (float*)d_ws;            // NCH*64
    float* Bar   = Aar + NCH * 64;          // NCH*64
    float* carry = Bar + NCH * 64;          // NCH*64
    uint4* abg   = (uint4*)(carry + NCH * 64);  // T*64*4 B = 134.2 MB packed ab

    aphase<<<NCH, 256, 0, stream>>>(x, W1, B1, Aar, Bar, abg);
    carry_scan<<<1, 1024, 0, stream>>>(Aar, Bar, carry);
    ephase<<<NCH, 256, 0, stream>>>(abg, carry, W2, B2, out);
}